// Round 5
// baseline (140.134 us; speedup 1.0000x reference)
//
#include <hip/hip_runtime.h>

#define S_LEN 1024
#define D_DIM 128
#define KVBLK 64
#define BH_N 128
#define M0_LOG2 2.0f   // fixed softmax base (log2 domain); |score*log2e| < 1 << 2

typedef __attribute__((ext_vector_type(8))) short short8;
typedef __attribute__((ext_vector_type(4))) short short4v;
typedef __attribute__((ext_vector_type(4))) float f32x4;
typedef __attribute__((ext_vector_type(16))) float f32x16;
typedef __attribute__((ext_vector_type(4))) unsigned int uint4v;

__device__ __forceinline__ unsigned short f2bf(float f) {
  union { float f; unsigned u; } x; x.f = f;
  unsigned r = x.u + 0x7fffu + ((x.u >> 16) & 1u);
  return (unsigned short)(r >> 16);
}

__device__ __forceinline__ short8 pack8(float4 a, float4 b) {
  short8 f;
  f[0] = (short)f2bf(a.x); f[1] = (short)f2bf(a.y);
  f[2] = (short)f2bf(a.z); f[3] = (short)f2bf(a.w);
  f[4] = (short)f2bf(b.x); f[5] = (short)f2bf(b.y);
  f[6] = (short)f2bf(b.z); f[7] = (short)f2bf(b.w);
  return f;
}

__device__ __forceinline__ void gload_lds16(const void* g, void* l) {
  __builtin_amdgcn_global_load_lds(
      (const __attribute__((address_space(1))) unsigned int*)g,
      (__attribute__((address_space(3))) unsigned int*)l, 16, 0, 0);
}

// ---------- prepass 1: K f32 -> bf16 row-major ----------
__global__ __launch_bounds__(256) void conv_k(const float* __restrict__ in,
                                              unsigned short* __restrict__ out,
                                              int n8) {
  int i = blockIdx.x * 256 + threadIdx.x;
  int stride = gridDim.x * 256;
  for (; i < n8; i += stride) {
    float4 a = ((const float4*)in)[i * 2];
    float4 b = ((const float4*)in)[i * 2 + 1];
    ((short8*)out)[i] = pack8(a, b);
  }
}

// ---------- prepass 2: V f32 [bh][s][d] -> bf16 VT [bh][d][s] ----------
__global__ __launch_bounds__(256) void conv_vt(const float* __restrict__ v,
                                               unsigned short* __restrict__ vt) {
  __shared__ unsigned short tile[64][72];
  int b = blockIdx.x;  // 128 bh * 16 s-tiles * 2 d-tiles = 4096
  int d0 = (b & 1) * 64;
  int s0 = ((b >> 1) & 15) * 64;
  int bh = b >> 5;
  int t = threadIdx.x;
  #pragma unroll
  for (int i = 0; i < 4; ++i) {
    int s = (t >> 4) + i * 16;
    int dl = (t & 15) * 4;
    float4 x = *(const float4*)(v + ((size_t)(bh * S_LEN) + s0 + s) * D_DIM + d0 + dl);
    tile[s][dl + 0] = f2bf(x.x); tile[s][dl + 1] = f2bf(x.y);
    tile[s][dl + 2] = f2bf(x.z); tile[s][dl + 3] = f2bf(x.w);
  }
  __syncthreads();
  #pragma unroll
  for (int i = 0; i < 2; ++i) {
    int j = i * 256 + t;
    int dl = j >> 3, sc = j & 7;
    short8 w;
    #pragma unroll
    for (int q = 0; q < 8; ++q) w[q] = (short)tile[sc * 8 + q][dl];
    *(short8*)(vt + ((size_t)(bh * D_DIM) + d0 + dl) * S_LEN + s0 + sc * 8) = w;
  }
}

// ---------- main attention: 32x32 MFMA, 4 waves x 32 q-rows, in-register P ----------
__global__ __launch_bounds__(256, 2) void attn_main(
    const float* __restrict__ qg, const unsigned short* __restrict__ kbf,
    const unsigned short* __restrict__ vtbf, float* __restrict__ og) {
  __shared__ unsigned short K_lds[2][KVBLK * D_DIM];   // 2 x 16 KB
  __shared__ unsigned short VT_lds[2][D_DIM * KVBLK];  // 2 x 16 KB

  const int tid = threadIdx.x;
  const int lane = tid & 63;
  const int wid = tid >> 6;   // 0..3
  const int l31 = lane & 31;
  const int hi = lane >> 5;   // 0/1

  const int bid = blockIdx.x;
  const int bh = (bid & 7) | ((bid >> 6) << 3);
  const int qt = (bid >> 3) & 7;

  const size_t base = (size_t)bh * (S_LEN * D_DIM);
  const int qw = qt * 128 + wid * 32;  // wave's first q row

  // Q B-frags (32x32x16): qf[c] = Q[qw + l31][c*16 + hi*8 .. +7], scaled by log2e/128
  short8 qf[8];
  {
    const float* qp = qg + base + (size_t)(qw + l31) * D_DIM + hi * 8;
    const float s = 0.0078125f * 1.44269504088896f;
    #pragma unroll
    for (int c = 0; c < 8; ++c) {
      float4 a = *(const float4*)(qp + c * 16);
      float4 b = *(const float4*)(qp + c * 16 + 4);
      a.x *= s; a.y *= s; a.z *= s; a.w *= s;
      b.x *= s; b.y *= s; b.z *= s; b.w *= s;
      qf[c] = pack8(a, b);
    }
  }

  // Per-lane softmax state for q-row qw + l31 (hi=0/1 lanes hold k-partials)
  float neg_m = -M0_LOG2;
  float l_r = 0.f;
  f32x16 o_acc[4];
  #pragma unroll
  for (int dt = 0; dt < 4; ++dt)
    #pragma unroll
    for (int r = 0; r < 16; ++r) o_acc[dt][r] = 0.f;

  const unsigned short* kb = kbf + (size_t)bh * (S_LEN * D_DIM);
  const unsigned short* vtb = vtbf + (size_t)bh * (D_DIM * S_LEN);

  // per-wave staging: K rows [wid*16, +16), VT d-rows [wid*32, +32)
  #define STAGE(buf, kv0)                                                      \
    {                                                                          \
      _Pragma("unroll")                                                        \
      for (int i = 0; i < 4; ++i) {                                            \
        int row = wid * 16 + i * 4 + (lane >> 4);                              \
        int c = lane & 15;                                                     \
        const unsigned short* src =                                            \
            kb + (size_t)((kv0) + row) * D_DIM + ((c ^ (row & 7)) * 8);        \
        gload_lds16(src, &K_lds[buf][(wid * 16 + i * 4) * D_DIM]);             \
      }                                                                        \
      _Pragma("unroll")                                                        \
      for (int i = 0; i < 4; ++i) {                                            \
        int drow = wid * 32 + i * 8 + (lane >> 3);                             \
        int c = lane & 7;                                                      \
        const unsigned short* src =                                            \
            vtb + (size_t)drow * S_LEN + (kv0) + ((c ^ (drow & 7)) * 8);       \
        gload_lds16(src, &VT_lds[buf][(wid * 32 + i * 8) * KVBLK]);            \
      }                                                                        \
    }

  STAGE(0, 0);
  __syncthreads();

  for (int t = 0; t < S_LEN / KVBLK; ++t) {
    const int cur = t & 1;
    if (t + 1 < S_LEN / KVBLK) STAGE(cur ^ 1, (t + 1) * KVBLK);

    // ---- swapped QK^T (32x32x16): sacc[ks] = K[ks*32..+32][:] * Q^T ----
    // D: col = l31 = q; row = (reg&3) + 8*(reg>>2) + 4*hi = local kv.
    f32x16 sacc[2];
    #pragma unroll
    for (int ks = 0; ks < 2; ++ks)
      #pragma unroll
      for (int r = 0; r < 16; ++r) sacc[ks][r] = neg_m;

    __builtin_amdgcn_s_setprio(1);
    #pragma unroll
    for (int c = 0; c < 8; ++c) {
      #pragma unroll
      for (int ks = 0; ks < 2; ++ks) {
        int row = ks * 32 + l31;
        int dc = 2 * c + hi;
        int sidx = row * 128 + ((dc ^ (row & 7)) * 8);
        short8 kf = *(const short8*)&K_lds[cur][sidx];
        sacc[ks] = __builtin_amdgcn_mfma_f32_32x32x16_bf16(kf, qf[c], sacc[ks], 0, 0, 0);
      }
    }
    __builtin_amdgcn_s_setprio(0);

    // ---- guard: escalate to exact online softmax if any score exceeds m ----
    float lmax = sacc[0][0];
    #pragma unroll
    for (int ks = 0; ks < 2; ++ks)
      #pragma unroll
      for (int r = 0; r < 16; ++r) lmax = fmaxf(lmax, sacc[ks][r]);
    if (__any(lmax > 0.f)) {  // never taken for bounded scores; exact fallback
      float a = fmaxf(lmax, __shfl_xor(lmax, 32));  // full row max for q = l31
      float delta = fmaxf(a, 0.f);
      neg_m -= delta;
      l_r *= exp2f(-delta);
      float ar[16];
      #pragma unroll
      for (int r = 0; r < 16; ++r)
        ar[r] = exp2f(-__shfl(delta, (r & 3) + 8 * (r >> 2) + 4 * hi, 64));
      #pragma unroll
      for (int dt = 0; dt < 4; ++dt)
        #pragma unroll
        for (int r = 0; r < 16; ++r) o_acc[dt][r] *= ar[r];
      #pragma unroll
      for (int ks = 0; ks < 2; ++ks)
        #pragma unroll
        for (int r = 0; r < 16; ++r) sacc[ks][r] -= delta;
    }

    // ---- per kv-subtile: exp2 -> pack -> permlane-assemble PA -> PV MFMA ----
    #pragma unroll
    for (int ks = 0; ks < 2; ++ks) {
      float p[16];
      #pragma unroll
      for (int r = 0; r < 16; ++r) p[r] = exp2f(sacc[ks][r]);
      // pairwise l accumulation
      float s0 = (p[0] + p[1]) + (p[2] + p[3]);
      float s1 = (p[4] + p[5]) + (p[6] + p[7]);
      float s2 = (p[8] + p[9]) + (p[10] + p[11]);
      float s3 = (p[12] + p[13]) + (p[14] + p[15]);
      l_r += (s0 + s1) + (s2 + s3);

      // pack: w[g][u] = bf16pair(p[4g+2u], p[4g+2u+1]) -> kv = 8g + 4hi + {2u, 2u+1}
      unsigned w[4][2];
      #pragma unroll
      for (int g = 0; g < 4; ++g) {
        asm("v_cvt_pk_bf16_f32 %0, %1, %2" : "=v"(w[g][0]) : "v"(p[4 * g]), "v"(p[4 * g + 1]));
        asm("v_cvt_pk_bf16_f32 %0, %1, %2" : "=v"(w[g][1]) : "v"(p[4 * g + 2]), "v"(p[4 * g + 3]));
      }

      // assemble PA frags for k-chunks c=0,1 (k = ks*32 + c*16 + 8*hi + 0..7):
      // permlane32_swap: a' = {a.lo, b.lo}, b' = {a.hi, b.hi}
      #pragma unroll
      for (int c = 0; c < 2; ++c) {
        asm volatile("v_permlane32_swap_b32 %0, %1" : "+v"(w[2 * c][0]), "+v"(w[2 * c + 1][0]));
        asm volatile("v_permlane32_swap_b32 %0, %1" : "+v"(w[2 * c][1]), "+v"(w[2 * c + 1][1]));
        uint4v pw;
        pw[0] = w[2 * c][0];      // kv base + {0,1}
        pw[1] = w[2 * c][1];      // kv base + {2,3}
        pw[2] = w[2 * c + 1][0];  // kv base + {4,5}
        pw[3] = w[2 * c + 1][1];  // kv base + {6,7}
        short8 pa = __builtin_bit_cast(short8, pw);

        __builtin_amdgcn_s_setprio(1);
        #pragma unroll
        for (int dt = 0; dt < 4; ++dt) {
          int vrow = dt * 32 + l31;
          int kc8 = ks * 4 + c * 2 + hi;  // 8-elem chunk index within 64 kv
          int vidx = vrow * 64 + ((kc8 ^ (vrow & 7)) * 8);
          short8 vf = *(const short8*)&VT_lds[cur][vidx];
          o_acc[dt] = __builtin_amdgcn_mfma_f32_32x32x16_bf16(pa, vf, o_acc[dt], 0, 0, 0);
        }
        __builtin_amdgcn_s_setprio(0);
      }
    }
    __syncthreads();
  }

  // ---- deferred l reduction + epilogue ----
  float lsum = l_r + __shfl_xor(l_r, 32);  // full denom for q = l31
  float linv = 1.0f / lsum;
  float lr16[16];
  #pragma unroll
  for (int r = 0; r < 16; ++r)
    lr16[r] = __shfl(linv, (r & 3) + 8 * (r >> 2) + 4 * hi, 64);
  #pragma unroll
  for (int dt = 0; dt < 4; ++dt) {
    #pragma unroll
    for (int r = 0; r < 16; ++r) {
      int qr = (r & 3) + 8 * (r >> 2) + 4 * hi;
      og[base + (size_t)(qw + qr) * D_DIM + dt * 32 + l31] = o_acc[dt][r] * lr16[r];
    }
  }
}

// ---------- fallback (fused, f32 inputs) if ws too small ----------
__global__ __launch_bounds__(256) void attn_fused(
    const float* __restrict__ qg, const float* __restrict__ kg,
    const float* __restrict__ vg, float* __restrict__ og) {
  __shared__ unsigned short K_lds[KVBLK * D_DIM];
  __shared__ unsigned short VT_lds[D_DIM * KVBLK];
  __shared__ unsigned short P_lds[4][16 * KVBLK];

  const int tid = threadIdx.x;
  const int lane = tid & 63;
  const int wid = tid >> 6;
  const int l15 = lane & 15;
  const int lg = lane >> 4;

  const int bid = blockIdx.x;
  const int bh = (bid & 7) | ((bid >> 7) << 3);
  const int qt = (bid >> 3) & 15;

  const size_t base = (size_t)bh * (S_LEN * D_DIM);
  const int qw = qt * 64 + wid * 16;

  short8 qf[4];
  {
    const float* qp = qg + base + (size_t)(qw + l15) * D_DIM + lg * 8;
    #pragma unroll
    for (int c = 0; c < 4; ++c) {
      float4 a = *(const float4*)(qp + c * 32);
      float4 b = *(const float4*)(qp + c * 32 + 4);
      const float s = 0.0078125f;
      a.x *= s; a.y *= s; a.z *= s; a.w *= s;
      b.x *= s; b.y *= s; b.z *= s; b.w *= s;
      qf[c] = pack8(a, b);
    }
  }

  float m_r[4], l_r[4];
  f32x4 o_acc[8];
  #pragma unroll
  for (int r = 0; r < 4; ++r) { m_r[r] = -INFINITY; l_r[r] = 0.f; }
  #pragma unroll
  for (int dt = 0; dt < 8; ++dt) o_acc[dt] = (f32x4){0.f, 0.f, 0.f, 0.f};

  for (int kv0 = 0; kv0 < S_LEN; kv0 += KVBLK) {
    {
      const float* kb = kg + base + (size_t)kv0 * D_DIM;
      #pragma unroll
      for (int c = tid; c < KVBLK * D_DIM / 8; c += 256) {
        int row = c >> 4, dc = c & 15;
        const float* p = kb + row * D_DIM + dc * 8;
        float4 a = *(const float4*)p;
        float4 b = *(const float4*)(p + 4);
        int sidx = row * 128 + ((dc * 8) ^ ((row & 7) << 3));
        *(short8*)&K_lds[sidx] = pack8(a, b);
      }
    }
    {
      const float* vb = vg + base + (size_t)kv0 * D_DIM;
      #pragma unroll
      for (int u = tid; u < (KVBLK / 4) * (D_DIM / 4); u += 256) {
        int ib = u & 15;
        int db = u >> 4;
        const float* p = vb + (ib * 4) * D_DIM + db * 4;
        float rr[4][4];
        #pragma unroll
        for (int c = 0; c < 4; ++c) {
          float4 t = *(const float4*)(p + c * D_DIM);
          rr[c][0] = t.x; rr[c][1] = t.y; rr[c][2] = t.z; rr[c][3] = t.w;
        }
        #pragma unroll
        for (int j = 0; j < 4; ++j) {
          short4v w;
          w[0] = (short)f2bf(rr[0][j]); w[1] = (short)f2bf(rr[1][j]);
          w[2] = (short)f2bf(rr[2][j]); w[3] = (short)f2bf(rr[3][j]);
          int row = db * 4 + j;
          int sidx = row * 64 + ((ib * 4) ^ ((row & 7) << 3));
          *(short4v*)&VT_lds[sidx] = w;
        }
      }
    }
    __syncthreads();

    f32x4 sacc[4];
    #pragma unroll
    for (int tc = 0; tc < 4; ++tc) sacc[tc] = (f32x4){0.f, 0.f, 0.f, 0.f};
    #pragma unroll
    for (int tc = 0; tc < 4; ++tc) {
      int row = tc * 16 + l15;
      #pragma unroll
      for (int ck = 0; ck < 4; ++ck) {
        int sidx = row * 128 + ((ck * 32 + lg * 8) ^ ((row & 7) << 3));
        short8 kf = *(const short8*)&K_lds[sidx];
        sacc[tc] = __builtin_amdgcn_mfma_f32_16x16x32_bf16(qf[ck], kf, sacc[tc], 0, 0, 0);
      }
    }

    float alpha[4], ps[4];
    #pragma unroll
    for (int r = 0; r < 4; ++r) {
      float a = fmaxf(fmaxf(sacc[0][r], sacc[1][r]), fmaxf(sacc[2][r], sacc[3][r]));
      a = fmaxf(a, __shfl_xor(a, 1));
      a = fmaxf(a, __shfl_xor(a, 2));
      a = fmaxf(a, __shfl_xor(a, 4));
      a = fmaxf(a, __shfl_xor(a, 8));
      float mn = fmaxf(m_r[r], a);
      alpha[r] = __expf(m_r[r] - mn);
      m_r[r] = mn;
      ps[r] = 0.f;
    }
    #pragma unroll
    for (int tc = 0; tc < 4; ++tc) {
      #pragma unroll
      for (int r = 0; r < 4; ++r) {
        float p = __expf(sacc[tc][r] - m_r[r]);
        ps[r] += p;
        int prow = lg * 4 + r;
        int pcol = tc * 16 + l15;
        P_lds[wid][prow * 64 + (pcol ^ ((prow & 7) << 3))] = f2bf(p);
      }
    }
    #pragma unroll
    for (int r = 0; r < 4; ++r) {
      float s = ps[r];
      s += __shfl_xor(s, 1); s += __shfl_xor(s, 2);
      s += __shfl_xor(s, 4); s += __shfl_xor(s, 8);
      l_r[r] = l_r[r] * alpha[r] + s;
    }
    #pragma unroll
    for (int dt = 0; dt < 8; ++dt) {
      #pragma unroll
      for (int r = 0; r < 4; ++r) o_acc[dt][r] *= alpha[r];
    }

    #pragma unroll
    for (int kc = 0; kc < 2; ++kc) {
      int pidx = l15 * 64 + ((kc * 32 + lg * 8) ^ ((l15 & 7) << 3));
      short8 pf = *(const short8*)&P_lds[wid][pidx];
      #pragma unroll
      for (int dt = 0; dt < 8; ++dt) {
        int vrow = dt * 16 + l15;
        int vidx = vrow * 64 + ((kc * 32 + lg * 8) ^ ((vrow & 7) << 3));
        short8 vf = *(const short8*)&VT_lds[vidx];
        o_acc[dt] = __builtin_amdgcn_mfma_f32_16x16x32_bf16(pf, vf, o_acc[dt], 0, 0, 0);
      }
    }
    __syncthreads();
  }

  #pragma unroll
  for (int r = 0; r < 4; ++r) {
    float inv = 1.0f / l_r[r];
    float* op = og + base + (size_t)(qw + lg * 4 + r) * D_DIM + l15;
    #pragma unroll
    for (int dt = 0; dt < 8; ++dt) op[dt * 16] = o_acc[dt][r] * inv;
  }
}

extern "C" void kernel_launch(void* const* d_in, const int* in_sizes, int n_in,
                              void* d_out, int out_size, void* d_ws, size_t ws_size,
                              hipStream_t stream) {
  const float* q = (const float*)d_in[0];
  const float* k = (const float*)d_in[1];
  const float* v = (const float*)d_in[2];
  float* o = (float*)d_out;

  const size_t n_elem = (size_t)BH_N * S_LEN * D_DIM;
  const size_t need = 2 * n_elem * sizeof(unsigned short);

  if (ws_size >= need) {
    unsigned short* kbf = (unsigned short*)d_ws;
    unsigned short* vtbf = kbf + n_elem;
    conv_k<<<dim3(2048), dim3(256), 0, stream>>>(k, kbf, (int)(n_elem / 8));
    conv_vt<<<dim3(4096), dim3(256), 0, stream>>>(v, vtbf);
    attn_main<<<dim3(1024), dim3(256), 0, stream>>>(q, kbf, vtbf, o);
  } else {
    attn_fused<<<dim3(2048), dim3(256), 0, stream>>>(q, k, v, o);
  }
}